// Round 4
// baseline (463.845 us; speedup 1.0000x reference)
//
#include <hip/hip_runtime.h>
#include <hip/hip_cooperative_groups.h>
#include <math.h>

namespace cg = cooperative_groups;

#define NG    64
#define NPG   2048
#define NTOT  (NG*NPG)     // 131072
#define ZD    64
#define PD    128
#define MH    256

typedef __attribute__((ext_vector_type(8))) short bf16x8;
typedef __attribute__((ext_vector_type(4))) float f32x4;

// ---------- helpers ----------
__device__ __forceinline__ unsigned short f2bf(float f){
  unsigned u = __float_as_uint(f);
  unsigned r = u + 0x7FFFu + ((u >> 16) & 1u);
  return (unsigned short)(r >> 16);
}
__device__ __forceinline__ float bf2f(unsigned short s){
  return __uint_as_float(((unsigned)s) << 16);
}
// gelu via exp2+rcp (no IEEE div sequence) — verified bit-compatible round 2
__device__ __forceinline__ float gelu_f(float x){
  float u = x * x;
  float a = fmaf(0.044715f, u, 1.0f);
  float e = __builtin_amdgcn_exp2f(-2.3022083f * x * a);
  return x * __builtin_amdgcn_rcpf(1.0f + e);
}

// ============================================================================
// Fused cooperative kernel: phase0 zero -> A pool+zstat -> B stats -> C final
// grid MUST be <= co-resident capacity (512 @ 256thr, 50176B LDS, 2 blk/CU)
// waves_per_eu(2,2): pin register budget to 256 VGPR — round 3 showed the
// compiler squeezing to 128 VGPR (4 waves/EU target) and spilling ~22 MB of
// phase-C accumulators to scratch (WRITE_SIZE 28.5 MB, MfmaUtil 1.3%).
// ============================================================================
__attribute__((amdgpu_waves_per_eu(2, 2)))
__global__ void __launch_bounds__(256)
fused_all(const float* __restrict__ x, const float* __restrict__ z,
          const float* __restrict__ W1, const float* __restrict__ b1,
          const float* __restrict__ gamma, const float* __restrict__ beta,
          const float* __restrict__ W2, const float* __restrict__ b2,
          float* __restrict__ pooled, float* __restrict__ St,
          float* __restrict__ C, float* __restrict__ Aj,
          float* __restrict__ cp, unsigned short* __restrict__ Wbf,
          float* __restrict__ out){
  __shared__ __align__(16) unsigned char smem[50176];
  cg::grid_group gg = cg::this_grid();
  int tid = threadIdx.x;
  int bid = blockIdx.x;
  int nb  = gridDim.x;

  // ---------------- phase 0: zero St (4096) + C (4096) ----------------
  if (bid < 32){
    int i = bid * 256 + tid;         // 0..8191
    if (i < 4096) St[i] = 0.f;
    else          C[i - 4096] = 0.f;
  }
  gg.sync();

  // ---------------- phase A: zstat (blocks 0..255) + pool units ----------------
  {
    unsigned short* s_zt = (unsigned short*)smem;       // 64*264 ushort = 33792 B
    float* s_cred = (float*)(smem + 33792);             // 4096 floats  = 16384 B

    if (bid < 256){
      // ---- zstat unit bid ----
      int blk = bid;
      int g = blk >> 2, q4 = blk & 3;
      int lane = tid & 63, wave = tid >> 6;
      int col = lane & 15, quad = lane >> 4;
      const float4* z4 = (const float4*)z + ((size_t)g * 2048 + q4 * 512) * 16;
      int d4 = col;
      int mg = quad;

      f32x4 acc[4][4];
      #pragma unroll
      for (int a = 0; a < 4; a++)
        #pragma unroll
        for (int b = 0; b < 4; b++) acc[a][b] = (f32x4)(0.f);
      float s0 = 0.f, s1 = 0.f, s2 = 0.f, s3 = 0.f;

      for (int ch = 0; ch < 2; ch++){
        #pragma unroll
        for (int rd = 0; rd < 4; rd++){
          int m0 = rd * 64 + wave * 16 + mg * 4;
          const float4* src = z4 + ch * 4096 + m0 * 16 + d4;
          float4 v0 = src[0];
          float4 v1 = src[16];
          float4 v2 = src[32];
          float4 v3 = src[48];
          s0 += v0.x + v1.x + v2.x + v3.x;
          s1 += v0.y + v1.y + v2.y + v3.y;
          s2 += v0.z + v1.z + v2.z + v3.z;
          s3 += v0.w + v1.w + v2.w + v3.w;
          int slot = m0 >> 3;
          int sub  = m0 & 4;
          int d0 = d4 * 4;
          {
            int d = d0 + 0; int ss = slot ^ ((d >> 3) & 7);
            ushort4 w = make_ushort4(f2bf(v0.x), f2bf(v1.x), f2bf(v2.x), f2bf(v3.x));
            *(ushort4*)&s_zt[d * 264 + ss * 8 + sub] = w;
          }
          {
            int d = d0 + 1; int ss = slot ^ ((d >> 3) & 7);
            ushort4 w = make_ushort4(f2bf(v0.y), f2bf(v1.y), f2bf(v2.y), f2bf(v3.y));
            *(ushort4*)&s_zt[d * 264 + ss * 8 + sub] = w;
          }
          {
            int d = d0 + 2; int ss = slot ^ ((d >> 3) & 7);
            ushort4 w = make_ushort4(f2bf(v0.z), f2bf(v1.z), f2bf(v2.z), f2bf(v3.z));
            *(ushort4*)&s_zt[d * 264 + ss * 8 + sub] = w;
          }
          {
            int d = d0 + 3; int ss = slot ^ ((d >> 3) & 7);
            ushort4 w = make_ushort4(f2bf(v0.w), f2bf(v1.w), f2bf(v2.w), f2bf(v3.w));
            *(ushort4*)&s_zt[d * 264 + ss * 8 + sub] = w;
          }
        }
        __syncthreads();
        #pragma unroll
        for (int ks = 0; ks < 2; ks++){
          bf16x8 fr[4];
          #pragma unroll
          for (int t = 0; t < 4; t++){
            int row = t * 16 + col;
            int ss  = (wave * 8 + ks * 4 + quad) ^ ((row >> 3) & 7);
            fr[t] = *(const bf16x8*)&s_zt[row * 264 + ss * 8];
          }
          #pragma unroll
          for (int mt = 0; mt < 4; mt++)
            #pragma unroll
            for (int nt = 0; nt < 4; nt++)
              acc[mt][nt] = __builtin_amdgcn_mfma_f32_16x16x32_bf16(fr[mt], fr[nt], acc[mt][nt], 0, 0, 0);
        }
        __syncthreads();
      }

      s0 += __shfl_xor(s0, 16); s0 += __shfl_xor(s0, 32);
      s1 += __shfl_xor(s1, 16); s1 += __shfl_xor(s1, 32);
      s2 += __shfl_xor(s2, 16); s2 += __shfl_xor(s2, 32);
      s3 += __shfl_xor(s3, 16); s3 += __shfl_xor(s3, 32);
      if (quad == 0){
        atomicAdd(&St[(d4 * 4 + 0) * 64 + g], s0);
        atomicAdd(&St[(d4 * 4 + 1) * 64 + g], s1);
        atomicAdd(&St[(d4 * 4 + 2) * 64 + g], s2);
        atomicAdd(&St[(d4 * 4 + 3) * 64 + g], s3);
      }

      #pragma unroll
      for (int w = 0; w < 4; w++){
        if (wave == w){
          #pragma unroll
          for (int mt = 0; mt < 4; mt++)
            #pragma unroll
            for (int nt = 0; nt < 4; nt++)
              #pragma unroll
              for (int r = 0; r < 4; r++){
                int p = mt * 16 + quad * 4 + r;
                int qc = nt * 16 + col;
                if (w == 0) s_cred[p * 64 + qc]  = acc[mt][nt][r];
                else        s_cred[p * 64 + qc] += acc[mt][nt][r];
              }
        }
        __syncthreads();
      }
      for (int f = tid; f < 4096; f += 256)
        atomicAdd(&C[f], s_cred[f]);
    }

    // ---- pool units ----
    // blocks 0..255: unit bid; blocks 256..511: units bid, bid+256, bid+512
    int u0 = bid, nu = (bid < 256) ? 1 : 3;
    for (int k = 0; k < nu; k++){
      int bi = u0 + k * 256;          // 0..1023
      int b  = bi >> 4;
      int oh = bi & 15;
      int c4 = tid & 63;
      int rq = tid >> 6;
      const float4* x4 = (const float4*)x;
      size_t base = (size_t)(b * NPG + oh * 128) * 64;
      float4 acc = make_float4(0.f, 0.f, 0.f, 0.f);
      #pragma unroll 8
      for (int i = 0; i < 32; i++){
        float4 v = x4[base + (size_t)(rq + i * 4) * 64 + c4];
        acc.x += v.x; acc.y += v.y; acc.z += v.z; acc.w += v.w;
      }
      __syncthreads();               // protect s_cred reuse (zstat tail / prev unit)
      s_cred[tid] = acc.x + acc.y + acc.z + acc.w;
      __syncthreads();
      if (tid < 8){
        float s = 0.f;
        #pragma unroll
        for (int w = 0; w < 4; w++)
          #pragma unroll
          for (int j = 0; j < 8; j++)
            s += s_cred[w * 64 + tid * 8 + j];
        pooled[b * PD + oh * 8 + tid] = s * (1.0f / 4096.0f);
      }
    }
  }
  gg.sync();

  // ---------------- phase B: k2 stats on blocks 0..63 ----------------
  if (bid < 64){
    float* pl = (float*)smem;        // 64*129 floats = 33024 B
    int jc = tid >> 6, lane = tid & 63;
    int j = bid * 4 + jc;

    Wbf[(size_t)j * 64 + lane] = f2bf(W1[(size_t)lane * 256 + j]);

    for (int idx = tid; idx < 8192; idx += 256)
      pl[(idx >> 7) * 129 + (idx & 127)] = pooled[idx];
    __syncthreads();

    float g = b1[j];
    #pragma unroll 8
    for (int k = 0; k < 128; k++)
      g = fmaf(pl[lane * 129 + k], W1[(size_t)(ZD + k) * MH + j], g);

    float wl = W1[(size_t)lane * MH + j];
    float t1 = 0.f, t2 = 0.f;
    #pragma unroll
    for (int q = 0; q < 64; q++){
      float wq = __uint_as_float(__builtin_amdgcn_readlane(__float_as_uint(wl), q));
      t1 = fmaf(C [q * 64 + lane], wq, t1);
      t2 = fmaf(St[q * 64 + lane], wq, t2);
    }
    float v_wcw = wl * t1;
    float v_gs  = g * t2;
    float v_s   = t2;
    float v_g   = g;
    float v_g2  = g * g;
    #pragma unroll
    for (int off = 32; off; off >>= 1){
      v_wcw += __shfl_xor(v_wcw, off);
      v_gs  += __shfl_xor(v_gs , off);
      v_s   += __shfl_xor(v_s  , off);
      v_g   += __shfl_xor(v_g  , off);
      v_g2  += __shfl_xor(v_g2 , off);
    }
    const float invN = 1.0f / (float)NTOT;
    float mean = v_s * invN + v_g * (1.0f / 64.0f);
    float eh2  = v_wcw * invN + 2.0f * invN * v_gs + v_g2 * (1.0f / 64.0f);
    float var  = eh2 - mean * mean;
    float aj = gamma[j] * rsqrtf(var + 1e-5f);
    if (lane == 0) Aj[j] = aj;
    cp[lane * MH + j] = fmaf(aj, g, beta[j] - aj * mean);
  }
  gg.sync();

  // ---------------- phase C: k3 tiles, grid-stride over 1024 units ----------------
  {
    unsigned short* zt = (unsigned short*)smem;          // 128*136 ushort = 34816 B
    float* slab = (float*)(smem + 34816);                // 2*384 floats   =  3072 B
    int lane = tid & 63, wave = tid >> 6;
    int wm = wave & 1, wn = wave >> 1;
    int col = lane & 15, quad = lane >> 4;
    int mbase = wm * 64, nbase = wn * 128;

    // hoist the 16 distinct B-fragments (Wbf) into registers: removes all
    // global-load latency from the MFMA loop (round-3 spill/latency fix)
    bf16x8 bfrag[2][8];
    #pragma unroll
    for (int p = 0; p < 2; p++)
      #pragma unroll
      for (int nt = 0; nt < 8; nt++)
        bfrag[p][nt] = *(const bf16x8*)&Wbf[(size_t)(nbase + nt * 16 + col) * 64 + p * 32 + quad * 8];

    for (int u = bid; u < 1024; u += nb){
      int n0 = u * 128;
      int g = u >> 4;

      const float4* z4 = (const float4*)z + (size_t)n0 * 16;
      __syncthreads();               // protect zt/slab across phases & units
      #pragma unroll
      for (int i = 0; i < 8; i++){
        int idx = tid + i * 256;
        int m = idx >> 4, d4 = idx & 15;
        float4 v = z4[idx];
        ushort4 h, l;
        h.x = f2bf(v.x); l.x = f2bf(v.x - bf2f(h.x));
        h.y = f2bf(v.y); l.y = f2bf(v.y - bf2f(h.y));
        h.z = f2bf(v.z); l.z = f2bf(v.z - bf2f(h.z));
        h.w = f2bf(v.w); l.w = f2bf(v.w - bf2f(h.w));
        *(ushort4*)&zt[m * 136 + d4 * 4]      = h;
        *(ushort4*)&zt[m * 136 + 64 + d4 * 4] = l;
      }
      __syncthreads();

      f32x4 acc[4][8];
      #pragma unroll
      for (int mt = 0; mt < 4; mt++)
        #pragma unroll
        for (int nt = 0; nt < 8; nt++) acc[mt][nt] = (f32x4)(0.f);

      #pragma unroll
      for (int ks = 0; ks < 4; ks++){
        int k0 = ks * 32;
        bf16x8 af[4];
        #pragma unroll
        for (int mt = 0; mt < 4; mt++)
          af[mt] = *(const bf16x8*)&zt[(mbase + mt * 16 + col) * 136 + k0 + quad * 8];
        #pragma unroll
        for (int nt = 0; nt < 8; nt++){
          #pragma unroll
          for (int mt = 0; mt < 4; mt++)
            acc[mt][nt] = __builtin_amdgcn_mfma_f32_16x16x32_bf16(af[mt], bfrag[ks & 1][nt], acc[mt][nt], 0, 0, 0);
        }
      }

      float aj[8], cj[8], w2a[8], w2b[8], w2c[8];
      #pragma unroll
      for (int nt = 0; nt < 8; nt++){
        int j = nbase + nt * 16 + col;
        aj[nt] = Aj[j];
        cj[nt] = cp[g * MH + j];
        w2a[nt] = W2[j * 3 + 0];
        w2b[nt] = W2[j * 3 + 1];
        w2c[nt] = W2[j * 3 + 2];
      }

      #pragma unroll
      for (int mt = 0; mt < 4; mt++){
        #pragma unroll
        for (int r = 0; r < 4; r++){
          float o0 = 0.f, o1 = 0.f, o2 = 0.f;
          #pragma unroll
          for (int nt = 0; nt < 8; nt++){
            float h  = fmaf(aj[nt], acc[mt][nt][r], cj[nt]);
            float ge = gelu_f(h);
            o0 = fmaf(ge, w2a[nt], o0);
            o1 = fmaf(ge, w2b[nt], o1);
            o2 = fmaf(ge, w2c[nt], o2);
          }
          #pragma unroll
          for (int off = 8; off; off >>= 1){
            o0 += __shfl_xor(o0, off);
            o1 += __shfl_xor(o1, off);
            o2 += __shfl_xor(o2, off);
          }
          if (col == 0){
            int node = mbase + mt * 16 + quad * 4 + r;
            slab[wn * 384 + node * 3 + 0] = o0;
            slab[wn * 384 + node * 3 + 1] = o1;
            slab[wn * 384 + node * 3 + 2] = o2;
          }
        }
      }
      __syncthreads();
      float b2v[3] = {b2[0], b2[1], b2[2]};
      for (int f = tid; f < 384; f += 256)
        out[(size_t)u * 384 + f] = slab[f] + slab[384 + f] + b2v[f % 3];
    }
  }
}

// ============================================================================
// Fallback 3-kernel path (proven @271.9us) in case cooperative launch fails
// ============================================================================
__launch_bounds__(256)
__global__ void k1_pool_zstat(const float* __restrict__ x, const float* __restrict__ z,
                              float* __restrict__ pooled, float* __restrict__ St,
                              float* __restrict__ C){
  __shared__ __align__(16) unsigned short s_zt[64 * 264];
  __shared__ float s_cred[4096];
  int tid = threadIdx.x;

  if (blockIdx.x >= 256){
    int bi = blockIdx.x - 256;
    int b  = bi >> 4;
    int oh = bi & 15;
    int c4 = tid & 63;
    int rq = tid >> 6;
    const float4* x4 = (const float4*)x;
    size_t base = (size_t)(b * NPG + oh * 128) * 64;
    float4 acc = make_float4(0.f, 0.f, 0.f, 0.f);
    #pragma unroll 8
    for (int i = 0; i < 32; i++){
      float4 v = x4[base + (size_t)(rq + i * 4) * 64 + c4];
      acc.x += v.x; acc.y += v.y; acc.z += v.z; acc.w += v.w;
    }
    s_cred[tid] = acc.x + acc.y + acc.z + acc.w;
    __syncthreads();
    if (tid < 8){
      float s = 0.f;
      #pragma unroll
      for (int w = 0; w < 4; w++)
        #pragma unroll
        for (int j = 0; j < 8; j++)
          s += s_cred[w * 64 + tid * 8 + j];
      pooled[b * PD + oh * 8 + tid] = s * (1.0f / 4096.0f);
    }
    return;
  }

  int blk = blockIdx.x;
  int g = blk >> 2, q4 = blk & 3;
  int lane = tid & 63, wave = tid >> 6;
  int col = lane & 15, quad = lane >> 4;
  const float4* z4 = (const float4*)z + ((size_t)g * 2048 + q4 * 512) * 16;
  int d4 = col;
  int mg = quad;

  f32x4 acc[4][4];
  #pragma unroll
  for (int a = 0; a < 4; a++)
    #pragma unroll
    for (int b = 0; b < 4; b++) acc[a][b] = (f32x4)(0.f);
  float s0 = 0.f, s1 = 0.f, s2 = 0.f, s3 = 0.f;

  for (int ch = 0; ch < 2; ch++){
    #pragma unroll
    for (int rd = 0; rd < 4; rd++){
      int m0 = rd * 64 + wave * 16 + mg * 4;
      const float4* src = z4 + ch * 4096 + m0 * 16 + d4;
      float4 v0 = src[0];
      float4 v1 = src[16];
      float4 v2 = src[32];
      float4 v3 = src[48];
      s0 += v0.x + v1.x + v2.x + v3.x;
      s1 += v0.y + v1.y + v2.y + v3.y;
      s2 += v0.z + v1.z + v2.z + v3.z;
      s3 += v0.w + v1.w + v2.w + v3.w;
      int slot = m0 >> 3;
      int sub  = m0 & 4;
      int d0 = d4 * 4;
      {
        int d = d0 + 0; int ss = slot ^ ((d >> 3) & 7);
        ushort4 w = make_ushort4(f2bf(v0.x), f2bf(v1.x), f2bf(v2.x), f2bf(v3.x));
        *(ushort4*)&s_zt[d * 264 + ss * 8 + sub] = w;
      }
      {
        int d = d0 + 1; int ss = slot ^ ((d >> 3) & 7);
        ushort4 w = make_ushort4(f2bf(v0.y), f2bf(v1.y), f2bf(v2.y), f2bf(v3.y));
        *(ushort4*)&s_zt[d * 264 + ss * 8 + sub] = w;
      }
      {
        int d = d0 + 2; int ss = slot ^ ((d >> 3) & 7);
        ushort4 w = make_ushort4(f2bf(v0.z), f2bf(v1.z), f2bf(v2.z), f2bf(v3.z));
        *(ushort4*)&s_zt[d * 264 + ss * 8 + sub] = w;
      }
      {
        int d = d0 + 3; int ss = slot ^ ((d >> 3) & 7);
        ushort4 w = make_ushort4(f2bf(v0.w), f2bf(v1.w), f2bf(v2.w), f2bf(v3.w));
        *(ushort4*)&s_zt[d * 264 + ss * 8 + sub] = w;
      }
    }
    __syncthreads();
    #pragma unroll
    for (int ks = 0; ks < 2; ks++){
      bf16x8 fr[4];
      #pragma unroll
      for (int t = 0; t < 4; t++){
        int row = t * 16 + col;
        int ss  = (wave * 8 + ks * 4 + quad) ^ ((row >> 3) & 7);
        fr[t] = *(const bf16x8*)&s_zt[row * 264 + ss * 8];
      }
      #pragma unroll
      for (int mt = 0; mt < 4; mt++)
        #pragma unroll
        for (int nt = 0; nt < 4; nt++)
          acc[mt][nt] = __builtin_amdgcn_mfma_f32_16x16x32_bf16(fr[mt], fr[nt], acc[mt][nt], 0, 0, 0);
    }
    __syncthreads();
  }

  s0 += __shfl_xor(s0, 16); s0 += __shfl_xor(s0, 32);
  s1 += __shfl_xor(s1, 16); s1 += __shfl_xor(s1, 32);
  s2 += __shfl_xor(s2, 16); s2 += __shfl_xor(s2, 32);
  s3 += __shfl_xor(s3, 16); s3 += __shfl_xor(s3, 32);
  if (quad == 0){
    atomicAdd(&St[(d4 * 4 + 0) * 64 + g], s0);
    atomicAdd(&St[(d4 * 4 + 1) * 64 + g], s1);
    atomicAdd(&St[(d4 * 4 + 2) * 64 + g], s2);
    atomicAdd(&St[(d4 * 4 + 3) * 64 + g], s3);
  }

  #pragma unroll
  for (int w = 0; w < 4; w++){
    if (wave == w){
      #pragma unroll
      for (int mt = 0; mt < 4; mt++)
        #pragma unroll
        for (int nt = 0; nt < 4; nt++)
          #pragma unroll
          for (int r = 0; r < 4; r++){
            int p = mt * 16 + quad * 4 + r;
            int qc = nt * 16 + col;
            if (w == 0) s_cred[p * 64 + qc]  = acc[mt][nt][r];
            else        s_cred[p * 64 + qc] += acc[mt][nt][r];
          }
    }
    __syncthreads();
  }
  for (int f = tid; f < 4096; f += 256)
    atomicAdd(&C[f], s_cred[f]);
}

__launch_bounds__(256)
__global__ void k2_stats(const float* __restrict__ pooled, const float* __restrict__ W1,
                         const float* __restrict__ b1, const float* __restrict__ gamma,
                         const float* __restrict__ beta, const float* __restrict__ C,
                         const float* __restrict__ St, float* __restrict__ Aj,
                         float* __restrict__ cprime, unsigned short* __restrict__ Wbf){
  __shared__ float pl[64 * 129];
  int tid = threadIdx.x;
  int jc = tid >> 6, lane = tid & 63;
  int j = blockIdx.x * 4 + jc;

  Wbf[(size_t)j * 64 + lane] = f2bf(W1[(size_t)lane * 256 + j]);

  for (int idx = tid; idx < 8192; idx += 256)
    pl[(idx >> 7) * 129 + (idx & 127)] = pooled[idx];
  __syncthreads();

  float g = b1[j];
  #pragma unroll 8
  for (int k = 0; k < 128; k++)
    g = fmaf(pl[lane * 129 + k], W1[(size_t)(ZD + k) * MH + j], g);

  float wl = W1[(size_t)lane * MH + j];
  float t1 = 0.f, t2 = 0.f;
  #pragma unroll
  for (int q = 0; q < 64; q++){
    float wq = __uint_as_float(__builtin_amdgcn_readlane(__float_as_uint(wl), q));
    t1 = fmaf(C [q * 64 + lane], wq, t1);
    t2 = fmaf(St[q * 64 + lane], wq, t2);
  }
  float v_wcw = wl * t1;
  float v_gs  = g * t2;
  float v_s   = t2;
  float v_g   = g;
  float v_g2  = g * g;
  #pragma unroll
  for (int off = 32; off; off >>= 1){
    v_wcw += __shfl_xor(v_wcw, off);
    v_gs  += __shfl_xor(v_gs , off);
    v_s   += __shfl_xor(v_s  , off);
    v_g   += __shfl_xor(v_g  , off);
    v_g2  += __shfl_xor(v_g2 , off);
  }
  const float invN = 1.0f / (float)NTOT;
  float mean = v_s * invN + v_g * (1.0f / 64.0f);
  float eh2  = v_wcw * invN + 2.0f * invN * v_gs + v_g2 * (1.0f / 64.0f);
  float var  = eh2 - mean * mean;
  float aj = gamma[j] * rsqrtf(var + 1e-5f);
  if (lane == 0) Aj[j] = aj;
  cprime[lane * MH + j] = fmaf(aj, g, beta[j] - aj * mean);
}

__launch_bounds__(256, 2)
__global__ void final_kernel(const float* __restrict__ z, const unsigned short* __restrict__ Wbf,
                             const float* __restrict__ Aj, const float* __restrict__ cp,
                             const float* __restrict__ W2, const float* __restrict__ b2,
                             float* __restrict__ out){
  __shared__ __align__(16) unsigned short zt[128 * 136];
  __shared__ float slab[2][384];
  int tid = threadIdx.x;
  int n0 = blockIdx.x * 128;
  int g = blockIdx.x >> 4;

  const float4* z4 = (const float4*)z + (size_t)n0 * 16;
  #pragma unroll
  for (int i = 0; i < 8; i++){
    int idx = tid + i * 256;
    int m = idx >> 4, d4 = idx & 15;
    float4 v = z4[idx];
    ushort4 h, l;
    h.x = f2bf(v.x); l.x = f2bf(v.x - bf2f(h.x));
    h.y = f2bf(v.y); l.y = f2bf(v.y - bf2f(h.y));
    h.z = f2bf(v.z); l.z = f2bf(v.z - bf2f(h.z));
    h.w = f2bf(v.w); l.w = f2bf(v.w - bf2f(h.w));
    *(ushort4*)&zt[m * 136 + d4 * 4]      = h;
    *(ushort4*)&zt[m * 136 + 64 + d4 * 4] = l;
  }
  __syncthreads();

  int lane = tid & 63, wave = tid >> 6;
  int wm = wave & 1, wn = wave >> 1;
  int col = lane & 15, quad = lane >> 4;
  int mbase = wm * 64, nbase = wn * 128;

  f32x4 acc[4][8];
  #pragma unroll
  for (int mt = 0; mt < 4; mt++)
    #pragma unroll
    for (int nt = 0; nt < 8; nt++) acc[mt][nt] = (f32x4)(0.f);

  #pragma unroll
  for (int ks = 0; ks < 4; ks++){
    int k0 = ks * 32;
    bf16x8 af[4];
    #pragma unroll
    for (int mt = 0; mt < 4; mt++)
      af[mt] = *(const bf16x8*)&zt[(mbase + mt * 16 + col) * 136 + k0 + quad * 8];
    #pragma unroll
    for (int nt = 0; nt < 8; nt++){
      bf16x8 bv = *(const bf16x8*)&Wbf[(size_t)(nbase + nt * 16 + col) * 64 + (ks & 1) * 32 + quad * 8];
      #pragma unroll
      for (int mt = 0; mt < 4; mt++)
        acc[mt][nt] = __builtin_amdgcn_mfma_f32_16x16x32_bf16(af[mt], bv, acc[mt][nt], 0, 0, 0);
    }
  }

  float aj[8], cj[8], w2a[8], w2b[8], w2c[8];
  #pragma unroll
  for (int nt = 0; nt < 8; nt++){
    int j = nbase + nt * 16 + col;
    aj[nt] = Aj[j];
    cj[nt] = cp[g * MH + j];
    w2a[nt] = W2[j * 3 + 0];
    w2b[nt] = W2[j * 3 + 1];
    w2c[nt] = W2[j * 3 + 2];
  }

  #pragma unroll
  for (int mt = 0; mt < 4; mt++){
    #pragma unroll
    for (int r = 0; r < 4; r++){
      float o0 = 0.f, o1 = 0.f, o2 = 0.f;
      #pragma unroll
      for (int nt = 0; nt < 8; nt++){
        float h  = fmaf(aj[nt], acc[mt][nt][r], cj[nt]);
        float ge = gelu_f(h);
        o0 = fmaf(ge, w2a[nt], o0);
        o1 = fmaf(ge, w2b[nt], o1);
        o2 = fmaf(ge, w2c[nt], o2);
      }
      #pragma unroll
      for (int off = 8; off; off >>= 1){
        o0 += __shfl_xor(o0, off);
        o1 += __shfl_xor(o1, off);
        o2 += __shfl_xor(o2, off);
      }
      if (col == 0){
        int node = mbase + mt * 16 + quad * 4 + r;
        slab[wn][node * 3 + 0] = o0;
        slab[wn][node * 3 + 1] = o1;
        slab[wn][node * 3 + 2] = o2;
      }
    }
  }
  __syncthreads();
  float b2v[3] = {b2[0], b2[1], b2[2]};
  for (int f = tid; f < 384; f += 256)
    out[(size_t)blockIdx.x * 384 + f] = slab[0][f] + slab[1][f] + b2v[f % 3];
}

// ---------- launch ----------
extern "C" void kernel_launch(void* const* d_in, const int* in_sizes, int n_in,
                              void* d_out, int out_size, void* d_ws, size_t ws_size,
                              hipStream_t stream){
  (void)in_sizes; (void)n_in; (void)out_size; (void)ws_size;
  const float* x     = (const float*)d_in[0];
  const float* z     = (const float*)d_in[2];
  const float* W1    = (const float*)d_in[3];
  const float* b1    = (const float*)d_in[4];
  const float* gamma = (const float*)d_in[5];
  const float* beta  = (const float*)d_in[6];
  const float* W2    = (const float*)d_in[7];
  const float* b2    = (const float*)d_in[8];
  float* out = (float*)d_out;

  float* W = (float*)d_ws;
  float* pooled = W;                         // 0     .. 8191
  float* St     = W + 8192;                  // 8192  .. 12287
  float* C      = W + 12288;                 // 12288 .. 16383  (contiguous after St)
  float* Aj     = W + 16384;                 // 16384 .. 16639
  float* CP     = W + 16640;                 // 16640 .. 33023
  unsigned short* Wbf = (unsigned short*)(W + 33024);  // 16384 ushorts

  void* args[] = {(void*)&x, (void*)&z, (void*)&W1, (void*)&b1, (void*)&gamma,
                  (void*)&beta, (void*)&W2, (void*)&b2, (void*)&pooled, (void*)&St,
                  (void*)&C, (void*)&Aj, (void*)&CP, (void*)&Wbf, (void*)&out};
  hipError_t err = hipLaunchCooperativeKernel((const void*)fused_all, dim3(512), dim3(256),
                                              args, 0, stream);
  if (err != hipSuccess){
    // fallback: proven 3-kernel path
    hipMemsetAsync((char*)d_ws + 8192 * 4, 0, 8192 * 4, stream);
    k1_pool_zstat<<<dim3(1280), dim3(256), 0, stream>>>(x, z, pooled, St, C);
    k2_stats     <<<dim3(64),   dim3(256), 0, stream>>>(pooled, W1, b1, gamma, beta, C, St, Aj, CP, Wbf);
    final_kernel <<<dim3(NTOT / 128), dim3(256), 0, stream>>>(z, Wbf, Aj, CP, W2, b2, out);
  }
}

// Round 5
// 270.802 us; speedup vs baseline: 1.7129x; 1.7129x over previous
//
#include <hip/hip_runtime.h>
#include <math.h>

#define NG    64
#define NPG   2048
#define NTOT  (NG*NPG)     // 131072
#define ZD    64
#define PD    128
#define MH    256

typedef __attribute__((ext_vector_type(8))) short bf16x8;
typedef __attribute__((ext_vector_type(4))) float f32x4;

// ---------- helpers ----------
__device__ __forceinline__ unsigned short f2bf(float f){
  unsigned u = __float_as_uint(f);
  unsigned r = u + 0x7FFFu + ((u >> 16) & 1u);
  return (unsigned short)(r >> 16);
}
__device__ __forceinline__ float bf2f(unsigned short s){
  return __uint_as_float(((unsigned)s) << 16);
}
// gelu via exp2+rcp (no IEEE div sequence) — verified bit-compatible round 2
__device__ __forceinline__ float gelu_f(float x){
  float u = x * x;
  float a = fmaf(0.044715f, u, 1.0f);
  float e = __builtin_amdgcn_exp2f(-2.3022083f * x * a);
  return x * __builtin_amdgcn_rcpf(1.0f + e);
}

// ---------- K1: fused pool (blocks 256..1279) + zstat (blocks 0..255) ----------
// unchanged from the proven 271.9us version (round 2)
__launch_bounds__(256)
__global__ void k1_pool_zstat(const float* __restrict__ x, const float* __restrict__ z,
                              float* __restrict__ pooled, float* __restrict__ St,
                              float* __restrict__ C){
  __shared__ __align__(16) unsigned short s_zt[64 * 264];  // 33792 B, [d][m] swizzled
  __shared__ float s_cred[4096];                           // 16384 B (pool reuses first 256)
  int tid = threadIdx.x;

  if (blockIdx.x >= 256){
    // ---- pool ----
    int bi = blockIdx.x - 256;
    int b  = bi >> 4;
    int oh = bi & 15;
    int c4 = tid & 63;
    int rq = tid >> 6;
    const float4* x4 = (const float4*)x;
    size_t base = (size_t)(b * NPG + oh * 128) * 64;
    float4 acc = make_float4(0.f, 0.f, 0.f, 0.f);
    #pragma unroll 8
    for (int i = 0; i < 32; i++){
      float4 v = x4[base + (size_t)(rq + i * 4) * 64 + c4];
      acc.x += v.x; acc.y += v.y; acc.z += v.z; acc.w += v.w;
    }
    s_cred[tid] = acc.x + acc.y + acc.z + acc.w;
    __syncthreads();
    if (tid < 8){
      float s = 0.f;
      #pragma unroll
      for (int w = 0; w < 4; w++)
        #pragma unroll
        for (int j = 0; j < 8; j++)
          s += s_cred[w * 64 + tid * 8 + j];
      pooled[b * PD + oh * 8 + tid] = s * (1.0f / 4096.0f);
    }
    return;
  }

  // ---- zstat ----
  int blk = blockIdx.x;           // 0..255
  int g = blk >> 2, q4 = blk & 3;
  int lane = tid & 63, wave = tid >> 6;
  int col = lane & 15, quad = lane >> 4;
  const float4* z4 = (const float4*)z + ((size_t)g * 2048 + q4 * 512) * 16;
  int d4 = col;
  int mg = quad;

  f32x4 acc[4][4];
  #pragma unroll
  for (int a = 0; a < 4; a++)
    #pragma unroll
    for (int b = 0; b < 4; b++) acc[a][b] = (f32x4)(0.f);
  float s0 = 0.f, s1 = 0.f, s2 = 0.f, s3 = 0.f;

  for (int ch = 0; ch < 2; ch++){
    #pragma unroll
    for (int rd = 0; rd < 4; rd++){
      int m0 = rd * 64 + wave * 16 + mg * 4;
      const float4* src = z4 + ch * 4096 + m0 * 16 + d4;
      float4 v0 = src[0];
      float4 v1 = src[16];
      float4 v2 = src[32];
      float4 v3 = src[48];
      s0 += v0.x + v1.x + v2.x + v3.x;
      s1 += v0.y + v1.y + v2.y + v3.y;
      s2 += v0.z + v1.z + v2.z + v3.z;
      s3 += v0.w + v1.w + v2.w + v3.w;
      int slot = m0 >> 3;
      int sub  = m0 & 4;
      int d0 = d4 * 4;
      {
        int d = d0 + 0; int ss = slot ^ ((d >> 3) & 7);
        ushort4 w = make_ushort4(f2bf(v0.x), f2bf(v1.x), f2bf(v2.x), f2bf(v3.x));
        *(ushort4*)&s_zt[d * 264 + ss * 8 + sub] = w;
      }
      {
        int d = d0 + 1; int ss = slot ^ ((d >> 3) & 7);
        ushort4 w = make_ushort4(f2bf(v0.y), f2bf(v1.y), f2bf(v2.y), f2bf(v3.y));
        *(ushort4*)&s_zt[d * 264 + ss * 8 + sub] = w;
      }
      {
        int d = d0 + 2; int ss = slot ^ ((d >> 3) & 7);
        ushort4 w = make_ushort4(f2bf(v0.z), f2bf(v1.z), f2bf(v2.z), f2bf(v3.z));
        *(ushort4*)&s_zt[d * 264 + ss * 8 + sub] = w;
      }
      {
        int d = d0 + 3; int ss = slot ^ ((d >> 3) & 7);
        ushort4 w = make_ushort4(f2bf(v0.w), f2bf(v1.w), f2bf(v2.w), f2bf(v3.w));
        *(ushort4*)&s_zt[d * 264 + ss * 8 + sub] = w;
      }
    }
    __syncthreads();
    #pragma unroll
    for (int ks = 0; ks < 2; ks++){
      bf16x8 fr[4];
      #pragma unroll
      for (int t = 0; t < 4; t++){
        int row = t * 16 + col;
        int ss  = (wave * 8 + ks * 4 + quad) ^ ((row >> 3) & 7);
        fr[t] = *(const bf16x8*)&s_zt[row * 264 + ss * 8];
      }
      #pragma unroll
      for (int mt = 0; mt < 4; mt++)
        #pragma unroll
        for (int nt = 0; nt < 4; nt++)
          acc[mt][nt] = __builtin_amdgcn_mfma_f32_16x16x32_bf16(fr[mt], fr[nt], acc[mt][nt], 0, 0, 0);
    }
    __syncthreads();
  }

  s0 += __shfl_xor(s0, 16); s0 += __shfl_xor(s0, 32);
  s1 += __shfl_xor(s1, 16); s1 += __shfl_xor(s1, 32);
  s2 += __shfl_xor(s2, 16); s2 += __shfl_xor(s2, 32);
  s3 += __shfl_xor(s3, 16); s3 += __shfl_xor(s3, 32);
  if (quad == 0){
    atomicAdd(&St[(d4 * 4 + 0) * 64 + g], s0);
    atomicAdd(&St[(d4 * 4 + 1) * 64 + g], s1);
    atomicAdd(&St[(d4 * 4 + 2) * 64 + g], s2);
    atomicAdd(&St[(d4 * 4 + 3) * 64 + g], s3);
  }

  #pragma unroll
  for (int w = 0; w < 4; w++){
    if (wave == w){
      #pragma unroll
      for (int mt = 0; mt < 4; mt++)
        #pragma unroll
        for (int nt = 0; nt < 4; nt++)
          #pragma unroll
          for (int r = 0; r < 4; r++){
            int p = mt * 16 + quad * 4 + r;
            int qc = nt * 16 + col;
            if (w == 0) s_cred[p * 64 + qc]  = acc[mt][nt][r];
            else        s_cred[p * 64 + qc] += acc[mt][nt][r];
          }
    }
    __syncthreads();
  }
  for (int f = tid; f < 4096; f += 256)
    atomicAdd(&C[f], s_cred[f]);
}

// ---------- K2: fused Wbf precompute + gmat + analytic BN stats (unchanged) ----------
__launch_bounds__(256)
__global__ void k2_stats(const float* __restrict__ pooled, const float* __restrict__ W1,
                         const float* __restrict__ b1, const float* __restrict__ gamma,
                         const float* __restrict__ beta, const float* __restrict__ C,
                         const float* __restrict__ St, float* __restrict__ Aj,
                         float* __restrict__ cprime, unsigned short* __restrict__ Wbf){
  __shared__ float pl[64 * 129];
  int tid = threadIdx.x;
  int jc = tid >> 6, lane = tid & 63;
  int j = blockIdx.x * 4 + jc;

  Wbf[(size_t)j * 64 + lane] = f2bf(W1[(size_t)lane * 256 + j]);

  for (int idx = tid; idx < 8192; idx += 256)
    pl[(idx >> 7) * 129 + (idx & 127)] = pooled[idx];
  __syncthreads();

  float g = b1[j];
  #pragma unroll 8
  for (int k = 0; k < 128; k++)
    g = fmaf(pl[lane * 129 + k], W1[(size_t)(ZD + k) * MH + j], g);

  float wl = W1[(size_t)lane * MH + j];
  float t1 = 0.f, t2 = 0.f;
  #pragma unroll
  for (int q = 0; q < 64; q++){
    float wq = __uint_as_float(__builtin_amdgcn_readlane(__float_as_uint(wl), q));
    t1 = fmaf(C [q * 64 + lane], wq, t1);
    t2 = fmaf(St[q * 64 + lane], wq, t2);
  }
  float v_wcw = wl * t1;
  float v_gs  = g * t2;
  float v_s   = t2;
  float v_g   = g;
  float v_g2  = g * g;
  #pragma unroll
  for (int off = 32; off; off >>= 1){
    v_wcw += __shfl_xor(v_wcw, off);
    v_gs  += __shfl_xor(v_gs , off);
    v_s   += __shfl_xor(v_s  , off);
    v_g   += __shfl_xor(v_g  , off);
    v_g2  += __shfl_xor(v_g2 , off);
  }
  const float invN = 1.0f / (float)NTOT;
  float mean = v_s * invN + v_g * (1.0f / 64.0f);
  float eh2  = v_wcw * invN + 2.0f * invN * v_gs + v_g2 * (1.0f / 64.0f);
  float var  = eh2 - mean * mean;
  float aj = gamma[j] * rsqrtf(var + 1e-5f);
  if (lane == 0) Aj[j] = aj;
  cprime[lane * MH + j] = fmaf(aj, g, beta[j] - aj * mean);
}

// ---------- K3: REBUILT — 64 nodes x 256 j per block (2048 blocks) ----------
// Round-4 diagnosis: old 128x256 tile needs acc[4][8]=128 f32/thread + working
// set ≈190 regs — spills inside the MFMA loop at any achievable budget (coop
// variant measured 28-57 MB scratch traffic, MfmaUtil 1.3%). New tile halves
// per-thread acc to acc[4][4]=64; peak pressure ~115 regs -> fits 128 at
// 4 waves/SIMD (launch_bounds(256,4)), no spills, 2x occupancy.
// Each of 4 waves computes all 64 nodes x its own 64 j; cross-wave j-sum via
// 4-slab LDS reduction in the epilogue.
__launch_bounds__(256, 4)
__global__ void final_kernel(const float* __restrict__ z, const unsigned short* __restrict__ Wbf,
                             const float* __restrict__ Aj, const float* __restrict__ cp,
                             const float* __restrict__ W2, const float* __restrict__ b2,
                             float* __restrict__ out){
  __shared__ __align__(16) unsigned short zt[64 * 136];  // [m][k0..127 = hi|lo], pad 8
  __shared__ float slab[4 * 192];                        // per-wave partial (64 nodes x 3)
  int tid = threadIdx.x;
  int u  = blockIdx.x;            // 0..2047
  int n0 = u * 64;
  int g  = u >> 5;                // 32 blocks per graph

  // stage z tile hi/lo: 64 rows x 16 d4 = 1024 float4, 256 threads x 4
  const float4* z4 = (const float4*)z + (size_t)n0 * 16;
  #pragma unroll
  for (int i = 0; i < 4; i++){
    int idx = tid + i * 256;
    int m = idx >> 4, d4 = idx & 15;
    float4 v = z4[idx];
    ushort4 h, l;
    h.x = f2bf(v.x); l.x = f2bf(v.x - bf2f(h.x));
    h.y = f2bf(v.y); l.y = f2bf(v.y - bf2f(h.y));
    h.z = f2bf(v.z); l.z = f2bf(v.z - bf2f(h.z));
    h.w = f2bf(v.w); l.w = f2bf(v.w - bf2f(h.w));
    *(ushort4*)&zt[m * 136 + d4 * 4]      = h;
    *(ushort4*)&zt[m * 136 + 64 + d4 * 4] = l;
  }
  __syncthreads();

  int lane = tid & 63, wave = tid >> 6;
  int col = lane & 15, quad = lane >> 4;
  int nbase = wave * 64;          // each wave owns 64 j-columns

  f32x4 acc[4][4];
  #pragma unroll
  for (int mt = 0; mt < 4; mt++)
    #pragma unroll
    for (int nt = 0; nt < 4; nt++) acc[mt][nt] = (f32x4)(0.f);

  #pragma unroll
  for (int ks = 0; ks < 4; ks++){
    int k0 = ks * 32;             // A: k over 0..127 (hi|lo); B: (ks&1)*32
    bf16x8 af[4];
    #pragma unroll
    for (int mt = 0; mt < 4; mt++)
      af[mt] = *(const bf16x8*)&zt[(mt * 16 + col) * 136 + k0 + quad * 8];
    #pragma unroll
    for (int nt = 0; nt < 4; nt++){
      bf16x8 bv = *(const bf16x8*)&Wbf[(size_t)(nbase + nt * 16 + col) * 64 + (ks & 1) * 32 + quad * 8];
      #pragma unroll
      for (int mt = 0; mt < 4; mt++)
        acc[mt][nt] = __builtin_amdgcn_mfma_f32_16x16x32_bf16(af[mt], bv, acc[mt][nt], 0, 0, 0);
    }
  }

  // per-lane j constants (loaded after MFMA loop to keep peak pressure low)
  float aj[4], cj[4], w2a[4], w2b[4], w2c[4];
  #pragma unroll
  for (int nt = 0; nt < 4; nt++){
    int j = nbase + nt * 16 + col;
    aj[nt] = Aj[j];
    cj[nt] = cp[g * MH + j];
    w2a[nt] = W2[j * 3 + 0];
    w2b[nt] = W2[j * 3 + 1];
    w2c[nt] = W2[j * 3 + 2];
  }

  // epilogue: BN affine -> GELU -> dot W2, reduce over this wave's 64 j
  #pragma unroll
  for (int mt = 0; mt < 4; mt++){
    #pragma unroll
    for (int r = 0; r < 4; r++){
      float o0 = 0.f, o1 = 0.f, o2 = 0.f;
      #pragma unroll
      for (int nt = 0; nt < 4; nt++){
        float h  = fmaf(aj[nt], acc[mt][nt][r], cj[nt]);
        float ge = gelu_f(h);
        o0 = fmaf(ge, w2a[nt], o0);
        o1 = fmaf(ge, w2b[nt], o1);
        o2 = fmaf(ge, w2c[nt], o2);
      }
      #pragma unroll
      for (int off = 8; off; off >>= 1){
        o0 += __shfl_xor(o0, off);
        o1 += __shfl_xor(o1, off);
        o2 += __shfl_xor(o2, off);
      }
      if (col == 0){
        int node = mt * 16 + quad * 4 + r;   // 0..63
        slab[wave * 192 + node * 3 + 0] = o0;
        slab[wave * 192 + node * 3 + 1] = o1;
        slab[wave * 192 + node * 3 + 2] = o2;
      }
    }
  }
  __syncthreads();
  if (tid < 192){
    float b2v = b2[tid % 3];
    out[(size_t)u * 192 + tid] = slab[tid] + slab[192 + tid] + slab[384 + tid] + slab[576 + tid] + b2v;
  }
}

// ---------- launch ----------
extern "C" void kernel_launch(void* const* d_in, const int* in_sizes, int n_in,
                              void* d_out, int out_size, void* d_ws, size_t ws_size,
                              hipStream_t stream){
  (void)in_sizes; (void)n_in; (void)out_size; (void)ws_size;
  const float* x     = (const float*)d_in[0];
  const float* z     = (const float*)d_in[2];
  const float* W1    = (const float*)d_in[3];
  const float* b1    = (const float*)d_in[4];
  const float* gamma = (const float*)d_in[5];
  const float* beta  = (const float*)d_in[6];
  const float* W2    = (const float*)d_in[7];
  const float* b2    = (const float*)d_in[8];
  float* out = (float*)d_out;

  float* W = (float*)d_ws;
  float* pooled = W;                         // 0     .. 8191
  float* St     = W + 8192;                  // 8192  .. 12287
  float* C      = W + 12288;                 // 12288 .. 16383
  float* Aj     = W + 16384;                 // 16384 .. 16639
  float* CP     = W + 16640;                 // 16640 .. 33023
  unsigned short* Wbf = (unsigned short*)(W + 33024);  // 16384 ushorts

  // zero St + C (contiguous 32 KB)
  hipMemsetAsync((char*)d_ws + 8192 * 4, 0, 8192 * 4, stream);

  k1_pool_zstat<<<dim3(1280), dim3(256), 0, stream>>>(x, z, pooled, St, C);
  k2_stats     <<<dim3(64),   dim3(256), 0, stream>>>(pooled, W1, b1, gamma, beta, C, St, Aj, CP, Wbf);
  final_kernel <<<dim3(NTOT / 64), dim3(256), 0, stream>>>(z, Wbf, Aj, CP, W2, b2, out);
}